// Round 14
// baseline (160.187 us; speedup 1.0000x reference)
//
#include <hip/hip_runtime.h>
#include <hip/hip_bf16.h>

#define D 128        // EMBED == LAYER == 128
#define BSHIFT 6     // 64 users per bucket
#define BUSERS (1 << BSHIFT)
#define NBLK 256     // blocks for hist/scatter passes
#define CHUNK 1280   // edges staged per bucket-chunk (avg bucket ~1024)
#define MROWS 64     // pw: item rows per block
#define NQ 4         // col quarters (phase-swept P working set ~4.2 MB < L2)
#define NKEY (NQ * BUSERS)

typedef __attribute__((ext_vector_type(8))) short bf16x8;
typedef __attribute__((ext_vector_type(4))) float f32x4;

// round-to-nearest f32 -> bf16 bits
__device__ __forceinline__ unsigned int bf16rn(float f) {
  unsigned int u = __float_as_uint(f);
  return (u + 0x7fffu + ((u >> 16) & 1u)) >> 16;
}

// ---------------------------------------------------------------------------
// Kernel 1 (fused): blocks [0, npw) run the MFMA pw GEMM; blocks [npw,
// npw+NBLK) run the bucket histogram (proven r13).
// ---------------------------------------------------------------------------
__global__ __launch_bounds__(256) void pw_hist_kernel(
    const float* __restrict__ emb, const float* __restrict__ W,
    unsigned short* __restrict__ Pb, int n_items, int npw,
    const int* __restrict__ rows, int* __restrict__ bcount, int n_edges,
    int epb, int nbuck) {
  __shared__ __align__(16) char smem[49152];
  const int tid = threadIdx.x;

  if ((int)blockIdx.x < npw) {
    unsigned short* Wt = (unsigned short*)smem;            // 32 KB swizzled
    unsigned short* At = (unsigned short*)(smem + 32768);  // 16 KB swizzled
    const int m0 = blockIdx.x * MROWS;

    for (int i = tid; i < 128 * 128; i += 256) {
      const int k = i >> 7, c = i & 127;
      const unsigned short v = (unsigned short)bf16rn(W[i]);
      const int boff = c * 256 + ((2 * k) ^ ((c & 7) << 4));
      *reinterpret_cast<unsigned short*>(reinterpret_cast<char*>(Wt) + boff) = v;
    }
    for (int i = tid; i < MROWS * 128; i += 256) {
      const int r = i >> 7, k = i & 127;
      const int gr = m0 + r;
      const float f = (gr < n_items) ? emb[(size_t)gr * 128 + k] : 0.f;
      const unsigned short v = (unsigned short)bf16rn(f);
      const int boff = r * 256 + ((2 * k) ^ ((r & 7) << 4));
      *reinterpret_cast<unsigned short*>(reinterpret_cast<char*>(At) + boff) = v;
    }
    __syncthreads();

    const int w = tid >> 6;
    const int lane = tid & 63;
    const int lr = lane & 15;
    const int lg = lane >> 4;

    bf16x8 a[4];
    {
      const int rloc = w * 16 + lr;
#pragma unroll
      for (int ks = 0; ks < 4; ++ks) {
        const int boff = rloc * 256 + (((ks * 64) + lg * 16) ^ ((lr & 7) << 4));
        a[ks] = *reinterpret_cast<const bf16x8*>(
            reinterpret_cast<const char*>(At) + boff);
      }
    }

    f32x4 acc[8];
#pragma unroll
    for (int cs = 0; cs < 8; ++cs) acc[cs] = {0.f, 0.f, 0.f, 0.f};

#pragma unroll
    for (int cs = 0; cs < 8; ++cs) {
      const int c = cs * 16 + lr;
#pragma unroll
      for (int ks = 0; ks < 4; ++ks) {
        const int boff = c * 256 + (((ks * 64) + lg * 16) ^ ((lr & 7) << 4));
        const bf16x8 b = *reinterpret_cast<const bf16x8*>(
            reinterpret_cast<const char*>(Wt) + boff);
        acc[cs] = __builtin_amdgcn_mfma_f32_16x16x32_bf16(a[ks], b, acc[cs],
                                                          0, 0, 0);
      }
    }

#pragma unroll
    for (int cs = 0; cs < 8; ++cs) {
      const int c = cs * 16 + lr;
#pragma unroll
      for (int reg = 0; reg < 4; ++reg) {
        const int r = m0 + w * 16 + lg * 4 + reg;
        if (r < n_items)
          Pb[(size_t)r * 128 + c] = (unsigned short)bf16rn(acc[cs][reg]);
      }
    }
  } else {
    int* h = (int*)smem;
    const int hb = blockIdx.x - npw;
    for (int b = tid; b < nbuck; b += 256) h[b] = 0;
    __syncthreads();
    const int e0 = hb * epb;
    const int e1 = (e0 + epb < n_edges) ? e0 + epb : n_edges;
    for (int e = e0 + tid; e < e1; e += 256)
      atomicAdd(&h[rows[e] >> BSHIFT], 1);
    __syncthreads();
    for (int b = tid; b < nbuck; b += 256)
      bcount[(size_t)b * NBLK + hb] = h[b];
  }
}

// ---------------------------------------------------------------------------
// 3-kernel exclusive scan over bcount (nbuck*NBLK entries) -> base.
// ---------------------------------------------------------------------------
__global__ __launch_bounds__(1024) void blocksum_kernel(
    const int* __restrict__ in, int* __restrict__ partials, int n) {
  __shared__ int lds[1024];
  const int tid = threadIdx.x;
  const int i = blockIdx.x * 1024 + tid;
  lds[tid] = (i < n) ? in[i] : 0;
  __syncthreads();
  for (int s = 512; s > 0; s >>= 1) {
    if (tid < s) lds[tid] += lds[tid + s];
    __syncthreads();
  }
  if (tid == 0) partials[blockIdx.x] = lds[0];
}

__global__ __launch_bounds__(1024) void scanpart_kernel(
    const int* __restrict__ partials, int* __restrict__ blockoff, int nb) {
  __shared__ int lds[1024];
  const int tid = threadIdx.x;
  const int x = (tid < nb) ? partials[tid] : 0;
  lds[tid] = x;
  __syncthreads();
  for (int s = 1; s < 1024; s <<= 1) {
    const int y = (tid >= s) ? lds[tid - s] : 0;
    __syncthreads();
    lds[tid] += y;
    __syncthreads();
  }
  if (tid < nb) blockoff[tid] = lds[tid] - x;
}

__global__ __launch_bounds__(1024) void localscan_kernel(
    const int* __restrict__ in, const int* __restrict__ blockoff,
    int* __restrict__ base, int n) {
  __shared__ int lds[1024];
  const int tid = threadIdx.x;
  const int i = blockIdx.x * 1024 + tid;
  const int x = (i < n) ? in[i] : 0;
  lds[tid] = x;
  __syncthreads();
  for (int s = 1; s < 1024; s <<= 1) {
    const int y = (tid >= s) ? lds[tid - s] : 0;
    __syncthreads();
    lds[tid] += y;
    __syncthreads();
  }
  if (i < n) base[i] = blockoff[blockIdx.x] + lds[tid] - x;
}

// ---------------------------------------------------------------------------
// Kernel 3: scatter pass — LDS cursors seeded by scanned base.
// ---------------------------------------------------------------------------
__global__ __launch_bounds__(256) void scatter2_kernel(
    const int* __restrict__ rows, const int* __restrict__ cols,
    const float* __restrict__ vals, const int* __restrict__ base,
    int2* __restrict__ sedge, int n_edges, int epb, int nbuck) {
  __shared__ int cur[1600];
  const int tid = threadIdx.x;
  for (int b = tid; b < nbuck; b += 256)
    cur[b] = base[(size_t)b * NBLK + blockIdx.x];
  __syncthreads();
  const int e0 = blockIdx.x * epb;
  const int e1 = (e0 + epb < n_edges) ? e0 + epb : n_edges;
  for (int e = e0 + tid; e < e1; e += 256) {
    const int r = rows[e];
    const int pos = atomicAdd(&cur[r >> BSHIFT], 1);
    sedge[pos] =
        make_int2(((r & (BUSERS - 1)) << 16) | cols[e], __float_as_int(vals[e]));
  }
}

// ---------------------------------------------------------------------------
// Kernel 4: per-bucket LDS counting-sort keyed by (col-quarter, user) +
// register accumulation in 4 ordered phases. All blocks sweep the same
// ~4.2 MB P quarter concurrently -> per-XCD L2-resident gather.
// ---------------------------------------------------------------------------
__global__ __launch_bounds__(256) void bucket_gather_kernel(
    const uint2* __restrict__ Pb2,  // bf16 quads, 32 uint2 per row
    const int* __restrict__ base, const int2* __restrict__ sedge,
    const float* __restrict__ nj, float* __restrict__ out, int n_users,
    int n_edges, int nbuck) {
  __shared__ int2 eraw[CHUNK];    // 10 KB
  __shared__ int2 esort[CHUNK];   // 10 KB
  __shared__ int cnt[NKEY];       // 1 KB
  __shared__ int incl[NKEY];      // 1 KB

  const int tid = threadIdx.x;
  const int b = blockIdx.x;
  const int u0 = b << BSHIFT;
  const int hw = tid >> 5;        // half-wave 0..7
  const int lane = tid & 31;

  const int beg = base[(size_t)b * NBLK];
  const int end = (b + 1 < nbuck) ? base[(size_t)(b + 1) * NBLK] : n_edges;

  float4 acc[8];
#pragma unroll
  for (int k = 0; k < 8; ++k) acc[k] = {0.f, 0.f, 0.f, 0.f};

  for (int cbeg = beg; cbeg < end; cbeg += CHUNK) {
    const int cnum = (cbeg + CHUNK < end) ? CHUNK : (end - cbeg);
    if (tid < NKEY) cnt[tid] = 0;
    __syncthreads();
    // stage chunk + count by key = (colQuarter<<6) | userLocal
    for (int i = tid; i < cnum; i += 256) {
      const int2 e = sedge[cbeg + i];
      eraw[i] = e;
      const int key = ((((unsigned int)e.x & 0xffffu) >> 14) << BSHIFT) |
                      (((unsigned int)e.x) >> 16);
      atomicAdd(&cnt[key], 1);
    }
    __syncthreads();
    // inclusive scan of NKEY=256 counts
    if (tid < NKEY) incl[tid] = cnt[tid];
    __syncthreads();
    for (int s = 1; s < NKEY; s <<= 1) {
      int y = 0;
      if (tid < NKEY && tid >= s) y = incl[tid - s];
      __syncthreads();
      if (tid < NKEY) incl[tid] += y;
      __syncthreads();
    }
    if (tid < NKEY) cnt[tid] = incl[tid] - cnt[tid];
    __syncthreads();
    // in-LDS scatter to (quarter, user)-sorted order
    for (int i = tid; i < cnum; i += 256) {
      const int2 e = eraw[i];
      const int key = ((((unsigned int)e.x & 0xffffu) >> 14) << BSHIFT) |
                      (((unsigned int)e.x) >> 16);
      const int pos = atomicAdd(&cnt[key], 1);
      esort[pos] = e;
    }
    __syncthreads();
    // register accumulate: 4 ordered quarter phases; half-wave per user;
    // 4-wide batches (avg segment ~4 edges)
    for (int q = 0; q < NQ; ++q) {
#pragma unroll
      for (int k = 0; k < 8; ++k) {
        const int idx = (q << BSHIFT) + hw * 8 + k;
        const int s = (idx == 0) ? 0 : incl[idx - 1];
        const int t = incl[idx];
        int j = s;
        for (; j + 3 < t; j += 4) {
          int2 e[4];
          uint2 p[4];
#pragma unroll
          for (int qq = 0; qq < 4; ++qq) e[qq] = esort[j + qq];
#pragma unroll
          for (int qq = 0; qq < 4; ++qq)
            p[qq] = Pb2[(size_t)(e[qq].x & 0xffff) * 32 + lane];
#pragma unroll
          for (int qq = 0; qq < 4; ++qq) {
            const float v = __int_as_float(e[qq].y);
            acc[k].x += v * __uint_as_float(p[qq].x << 16);
            acc[k].y += v * __uint_as_float(p[qq].x & 0xffff0000u);
            acc[k].z += v * __uint_as_float(p[qq].y << 16);
            acc[k].w += v * __uint_as_float(p[qq].y & 0xffff0000u);
          }
        }
        for (; j < t; ++j) {
          const int2 e0 = esort[j];
          const uint2 p0 = Pb2[(size_t)(e0.x & 0xffff) * 32 + lane];
          const float v0 = __int_as_float(e0.y);
          acc[k].x += v0 * __uint_as_float(p0.x << 16);
          acc[k].y += v0 * __uint_as_float(p0.x & 0xffff0000u);
          acc[k].z += v0 * __uint_as_float(p0.y << 16);
          acc[k].w += v0 * __uint_as_float(p0.y & 0xffff0000u);
        }
      }
    }
    __syncthreads();  // protect LDS before next chunk
  }

  // epilogue: scale by nj, full-row coalesced float4 stores
#pragma unroll
  for (int k = 0; k < 8; ++k) {
    const int u = u0 + hw * 8 + k;
    if (u < n_users) {
      const float s = nj[u];
      float4 a = acc[k];
      a.x *= s; a.y *= s; a.z *= s; a.w *= s;
      *reinterpret_cast<float4*>(out + (size_t)u * D + lane * 4) = a;
    }
  }
}

extern "C" void kernel_launch(void* const* d_in, const int* in_sizes, int n_in,
                              void* d_out, int out_size, void* d_ws,
                              size_t ws_size, hipStream_t stream) {
  const float* item_emb = (const float*)d_in[0];  // [n_items, 128]
  const float* user_nj  = (const float*)d_in[1];  // [n_users, 1]
  const float* weight   = (const float*)d_in[2];  // [128, 128]
  const float* adj_vals = (const float*)d_in[3];  // [E]
  const int*   adj_rows = (const int*)d_in[4];    // [E]
  const int*   adj_cols = (const int*)d_in[5];    // [E]

  const int n_items = in_sizes[0] / D;
  const int n_users = in_sizes[1];
  const int n_edges = in_sizes[3];
  float* out = (float*)d_out;

  const int nbuck = (n_users + BUSERS - 1) >> BSHIFT;  // 1563
  const int npw = (n_items + MROWS - 1) / MROWS;       // 782
  const int epb = (n_edges + NBLK - 1) / NBLK;         // 6250
  const int n_scan = nbuck * NBLK;                     // 400128
  const int nb_scan = (n_scan + 1023) / 1024;          // 391

  // ---- workspace layout (256B-aligned) ----
  auto align256 = [](size_t x) { return (x + 255) & ~(size_t)255; };
  char* ws = (char*)d_ws;
  size_t off = 0;
  unsigned short* Pb = (unsigned short*)(ws + off);
  off = align256(off + (size_t)n_items * D * 2);  // 12.8 MB
  int* bcount = (int*)(ws + off);  off = align256(off + (size_t)n_scan * 4);
  int* base = (int*)(ws + off);    off = align256(off + (size_t)n_scan * 4);
  int2* sedge = (int2*)(ws + off); off = align256(off + (size_t)n_edges * 8);
  int* partials = (int*)(ws + off); off = align256(off + (size_t)nb_scan * 4);
  int* blockoff = (int*)(ws + off); off = align256(off + (size_t)nb_scan * 4);

  // 1) fused: pw GEMM (blocks [0,npw)) || bucket histograms ([npw, npw+NBLK))
  pw_hist_kernel<<<npw + NBLK, 256, 0, stream>>>(
      item_emb, weight, Pb, n_items, npw, adj_rows, bcount, n_edges, epb,
      nbuck);

  // 2) 3-kernel exclusive scan of bcount -> base (no inter-block comms)
  blocksum_kernel<<<nb_scan, 1024, 0, stream>>>(bcount, partials, n_scan);
  scanpart_kernel<<<1, 1024, 0, stream>>>(partials, blockoff, nb_scan);
  localscan_kernel<<<nb_scan, 1024, 0, stream>>>(bcount, blockoff, base,
                                                 n_scan);

  // 3) scatter edges into bucket-sorted order (no global atomics)
  scatter2_kernel<<<NBLK, 256, 0, stream>>>(adj_rows, adj_cols, adj_vals, base,
                                            sedge, n_edges, epb, nbuck);

  // 4) per-bucket (quarter,user) counting-sort + phased register gather
  bucket_gather_kernel<<<nbuck, 256, 0, stream>>>(
      reinterpret_cast<const uint2*>(Pb), base, sedge, user_nj, out,
      n_users, n_edges, nbuck);
}

// Round 17
// 147.524 us; speedup vs baseline: 1.0858x; 1.0858x over previous
//
#include <hip/hip_runtime.h>
#include <hip/hip_bf16.h>

#define D 128        // EMBED == LAYER == 128
#define BSHIFT 6     // 64 users per bucket
#define BUSERS (1 << BSHIFT)
#define NBLK 256     // blocks for hist/scatter passes
#define CHUNK 1280   // edges staged per bucket-chunk (avg bucket ~1024)
#define MROWS 64     // pw: item rows per block

typedef __attribute__((ext_vector_type(8))) short bf16x8;
typedef __attribute__((ext_vector_type(4))) float f32x4;

// round-to-nearest f32 -> bf16 bits
__device__ __forceinline__ unsigned int bf16rn(float f) {
  unsigned int u = __float_as_uint(f);
  return (u + 0x7fffu + ((u >> 16) & 1u)) >> 16;
}

// ---------------------------------------------------------------------------
// Kernel 1 (fused): blocks [0, npw) run the MFMA pw GEMM; blocks [npw,
// npw+NBLK) run the bucket histogram (proven r13).
// ---------------------------------------------------------------------------
__global__ __launch_bounds__(256) void pw_hist_kernel(
    const float* __restrict__ emb, const float* __restrict__ W,
    unsigned short* __restrict__ Pb, int n_items, int npw,
    const int* __restrict__ rows, int* __restrict__ bcount, int n_edges,
    int epb, int nbuck) {
  __shared__ __align__(16) char smem[49152];
  const int tid = threadIdx.x;

  if ((int)blockIdx.x < npw) {
    unsigned short* Wt = (unsigned short*)smem;            // 32 KB swizzled
    unsigned short* At = (unsigned short*)(smem + 32768);  // 16 KB swizzled
    const int m0 = blockIdx.x * MROWS;

    for (int i = tid; i < 128 * 128; i += 256) {
      const int k = i >> 7, c = i & 127;
      const unsigned short v = (unsigned short)bf16rn(W[i]);
      const int boff = c * 256 + ((2 * k) ^ ((c & 7) << 4));
      *reinterpret_cast<unsigned short*>(reinterpret_cast<char*>(Wt) + boff) = v;
    }
    for (int i = tid; i < MROWS * 128; i += 256) {
      const int r = i >> 7, k = i & 127;
      const int gr = m0 + r;
      const float f = (gr < n_items) ? emb[(size_t)gr * 128 + k] : 0.f;
      const unsigned short v = (unsigned short)bf16rn(f);
      const int boff = r * 256 + ((2 * k) ^ ((r & 7) << 4));
      *reinterpret_cast<unsigned short*>(reinterpret_cast<char*>(At) + boff) = v;
    }
    __syncthreads();

    const int w = tid >> 6;
    const int lane = tid & 63;
    const int lr = lane & 15;
    const int lg = lane >> 4;

    bf16x8 a[4];
    {
      const int rloc = w * 16 + lr;
#pragma unroll
      for (int ks = 0; ks < 4; ++ks) {
        const int boff = rloc * 256 + (((ks * 64) + lg * 16) ^ ((lr & 7) << 4));
        a[ks] = *reinterpret_cast<const bf16x8*>(
            reinterpret_cast<const char*>(At) + boff);
      }
    }

    f32x4 acc[8];
#pragma unroll
    for (int cs = 0; cs < 8; ++cs) acc[cs] = {0.f, 0.f, 0.f, 0.f};

#pragma unroll
    for (int cs = 0; cs < 8; ++cs) {
      const int c = cs * 16 + lr;
#pragma unroll
      for (int ks = 0; ks < 4; ++ks) {
        const int boff = c * 256 + (((ks * 64) + lg * 16) ^ ((lr & 7) << 4));
        const bf16x8 b = *reinterpret_cast<const bf16x8*>(
            reinterpret_cast<const char*>(Wt) + boff);
        acc[cs] = __builtin_amdgcn_mfma_f32_16x16x32_bf16(a[ks], b, acc[cs],
                                                          0, 0, 0);
      }
    }

#pragma unroll
    for (int cs = 0; cs < 8; ++cs) {
      const int c = cs * 16 + lr;
#pragma unroll
      for (int reg = 0; reg < 4; ++reg) {
        const int r = m0 + w * 16 + lg * 4 + reg;
        if (r < n_items)
          Pb[(size_t)r * 128 + c] = (unsigned short)bf16rn(acc[cs][reg]);
      }
    }
  } else {
    int* h = (int*)smem;
    const int hb = blockIdx.x - npw;
    for (int b = tid; b < nbuck; b += 256) h[b] = 0;
    __syncthreads();
    const int e0 = hb * epb;
    const int e1 = (e0 + epb < n_edges) ? e0 + epb : n_edges;
    for (int e = e0 + tid; e < e1; e += 256)
      atomicAdd(&h[rows[e] >> BSHIFT], 1);
    __syncthreads();
    for (int b = tid; b < nbuck; b += 256)
      bcount[(size_t)b * NBLK + hb] = h[b];
  }
}

// ---------------------------------------------------------------------------
// 3-kernel exclusive scan over bcount (nbuck*NBLK entries) -> base.
// ---------------------------------------------------------------------------
__global__ __launch_bounds__(1024) void blocksum_kernel(
    const int* __restrict__ in, int* __restrict__ partials, int n) {
  __shared__ int lds[1024];
  const int tid = threadIdx.x;
  const int i = blockIdx.x * 1024 + tid;
  lds[tid] = (i < n) ? in[i] : 0;
  __syncthreads();
  for (int s = 512; s > 0; s >>= 1) {
    if (tid < s) lds[tid] += lds[tid + s];
    __syncthreads();
  }
  if (tid == 0) partials[blockIdx.x] = lds[0];
}

__global__ __launch_bounds__(1024) void scanpart_kernel(
    const int* __restrict__ partials, int* __restrict__ blockoff, int nb) {
  __shared__ int lds[1024];
  const int tid = threadIdx.x;
  const int x = (tid < nb) ? partials[tid] : 0;
  lds[tid] = x;
  __syncthreads();
  for (int s = 1; s < 1024; s <<= 1) {
    const int y = (tid >= s) ? lds[tid - s] : 0;
    __syncthreads();
    lds[tid] += y;
    __syncthreads();
  }
  if (tid < nb) blockoff[tid] = lds[tid] - x;
}

__global__ __launch_bounds__(1024) void localscan_kernel(
    const int* __restrict__ in, const int* __restrict__ blockoff,
    int* __restrict__ base, int n) {
  __shared__ int lds[1024];
  const int tid = threadIdx.x;
  const int i = blockIdx.x * 1024 + tid;
  const int x = (i < n) ? in[i] : 0;
  lds[tid] = x;
  __syncthreads();
  for (int s = 1; s < 1024; s <<= 1) {
    const int y = (tid >= s) ? lds[tid - s] : 0;
    __syncthreads();
    lds[tid] += y;
    __syncthreads();
  }
  if (i < n) base[i] = blockoff[blockIdx.x] + lds[tid] - x;
}

// ---------------------------------------------------------------------------
// Kernel 3: scatter pass — LDS cursors seeded by scanned base.
// ---------------------------------------------------------------------------
__global__ __launch_bounds__(256) void scatter2_kernel(
    const int* __restrict__ rows, const int* __restrict__ cols,
    const float* __restrict__ vals, const int* __restrict__ base,
    int2* __restrict__ sedge, int n_edges, int epb, int nbuck) {
  __shared__ int cur[1600];
  const int tid = threadIdx.x;
  for (int b = tid; b < nbuck; b += 256)
    cur[b] = base[(size_t)b * NBLK + blockIdx.x];
  __syncthreads();
  const int e0 = blockIdx.x * epb;
  const int e1 = (e0 + epb < n_edges) ? e0 + epb : n_edges;
  for (int e = e0 + tid; e < e1; e += 256) {
    const int r = rows[e];
    const int pos = atomicAdd(&cur[r >> BSHIFT], 1);
    sedge[pos] =
        make_int2(((r & (BUSERS - 1)) << 16) | cols[e], __float_as_int(vals[e]));
  }
}

// ---------------------------------------------------------------------------
// Kernel 4: per-bucket 64-key LDS counting-sort + register accumulation.
// QUARTER-WAVE per user: 16 lanes own a full P row (16 uint4 per row — 128
// bf16 = 256 B). 16 quarter-waves x 4 users; 8-wide batches -> 32 edges in
// flight per wave (2x the half-wave layout), same VALU work.
// ---------------------------------------------------------------------------
__global__ __launch_bounds__(256) void bucket_gather_kernel(
    const uint4* __restrict__ Pb4,  // bf16 octs, 16 uint4 per row
    const int* __restrict__ base, const int2* __restrict__ sedge,
    const float* __restrict__ nj, float* __restrict__ out, int n_users,
    int n_edges, int nbuck) {
  __shared__ int2 eraw[CHUNK];    // 10 KB
  __shared__ int2 esort[CHUNK];   // 10 KB
  __shared__ int cnt[BUSERS];
  __shared__ int incl[BUSERS];

  const int tid = threadIdx.x;
  const int b = blockIdx.x;
  const int u0 = b << BSHIFT;
  const int qw = tid >> 4;        // quarter-wave 0..15
  const int l16 = tid & 15;       // lane within quarter-wave

  const int beg = base[(size_t)b * NBLK];
  const int end = (b + 1 < nbuck) ? base[(size_t)(b + 1) * NBLK] : n_edges;

  float4 acc0[4], acc1[4];        // 4 users x 8 cols
#pragma unroll
  for (int k = 0; k < 4; ++k) {
    acc0[k] = {0.f, 0.f, 0.f, 0.f};
    acc1[k] = {0.f, 0.f, 0.f, 0.f};
  }

  for (int cbeg = beg; cbeg < end; cbeg += CHUNK) {
    const int cnum = (cbeg + CHUNK < end) ? CHUNK : (end - cbeg);
    if (tid < BUSERS) cnt[tid] = 0;
    __syncthreads();
    for (int i = tid; i < cnum; i += 256) {
      const int2 e = sedge[cbeg + i];
      eraw[i] = e;
      atomicAdd(&cnt[((unsigned int)e.x) >> 16], 1);
    }
    __syncthreads();
    if (tid < BUSERS) incl[tid] = cnt[tid];
    __syncthreads();
    for (int s = 1; s < BUSERS; s <<= 1) {
      int y = 0;
      if (tid < BUSERS && tid >= s) y = incl[tid - s];
      __syncthreads();
      if (tid < BUSERS) incl[tid] += y;
      __syncthreads();
    }
    if (tid < BUSERS) cnt[tid] = incl[tid] - cnt[tid];
    __syncthreads();
    for (int i = tid; i < cnum; i += 256) {
      const int2 e = eraw[i];
      const int pos = atomicAdd(&cnt[((unsigned int)e.x) >> 16], 1);
      esort[pos] = e;
    }
    __syncthreads();
    // register accumulate: quarter-wave per user, 8-wide MLP
#pragma unroll
    for (int k = 0; k < 4; ++k) {
      const int ul = qw * 4 + k;
      const int s = (ul == 0) ? 0 : incl[ul - 1];
      const int t = incl[ul];
      int j = s;
      for (; j + 7 < t; j += 8) {
        int2 e[8];
        uint4 p[8];
#pragma unroll
        for (int q = 0; q < 8; ++q) e[q] = esort[j + q];
#pragma unroll
        for (int q = 0; q < 8; ++q)
          p[q] = Pb4[(size_t)(e[q].x & 0xffff) * 16 + l16];
#pragma unroll
        for (int q = 0; q < 8; ++q) {
          const float v = __int_as_float(e[q].y);
          acc0[k].x += v * __uint_as_float(p[q].x << 16);
          acc0[k].y += v * __uint_as_float(p[q].x & 0xffff0000u);
          acc0[k].z += v * __uint_as_float(p[q].y << 16);
          acc0[k].w += v * __uint_as_float(p[q].y & 0xffff0000u);
          acc1[k].x += v * __uint_as_float(p[q].z << 16);
          acc1[k].y += v * __uint_as_float(p[q].z & 0xffff0000u);
          acc1[k].z += v * __uint_as_float(p[q].w << 16);
          acc1[k].w += v * __uint_as_float(p[q].w & 0xffff0000u);
        }
      }
      for (; j < t; ++j) {
        const int2 e0 = esort[j];
        const uint4 p0 = Pb4[(size_t)(e0.x & 0xffff) * 16 + l16];
        const float v0 = __int_as_float(e0.y);
        acc0[k].x += v0 * __uint_as_float(p0.x << 16);
        acc0[k].y += v0 * __uint_as_float(p0.x & 0xffff0000u);
        acc0[k].z += v0 * __uint_as_float(p0.y << 16);
        acc0[k].w += v0 * __uint_as_float(p0.y & 0xffff0000u);
        acc1[k].x += v0 * __uint_as_float(p0.z << 16);
        acc1[k].y += v0 * __uint_as_float(p0.z & 0xffff0000u);
        acc1[k].z += v0 * __uint_as_float(p0.w << 16);
        acc1[k].w += v0 * __uint_as_float(p0.w & 0xffff0000u);
      }
    }
    __syncthreads();  // protect LDS before next chunk
  }

  // epilogue: scale by nj, two coalesced float4 stores per lane
#pragma unroll
  for (int k = 0; k < 4; ++k) {
    const int u = u0 + qw * 4 + k;
    if (u < n_users) {
      const float s = nj[u];
      float4 a0 = acc0[k], a1 = acc1[k];
      a0.x *= s; a0.y *= s; a0.z *= s; a0.w *= s;
      a1.x *= s; a1.y *= s; a1.z *= s; a1.w *= s;
      float* o = out + (size_t)u * D + l16 * 8;
      *reinterpret_cast<float4*>(o) = a0;
      *reinterpret_cast<float4*>(o + 4) = a1;
    }
  }
}

extern "C" void kernel_launch(void* const* d_in, const int* in_sizes, int n_in,
                              void* d_out, int out_size, void* d_ws,
                              size_t ws_size, hipStream_t stream) {
  const float* item_emb = (const float*)d_in[0];  // [n_items, 128]
  const float* user_nj  = (const float*)d_in[1];  // [n_users, 1]
  const float* weight   = (const float*)d_in[2];  // [128, 128]
  const float* adj_vals = (const float*)d_in[3];  // [E]
  const int*   adj_rows = (const int*)d_in[4];    // [E]
  const int*   adj_cols = (const int*)d_in[5];    // [E]

  const int n_items = in_sizes[0] / D;
  const int n_users = in_sizes[1];
  const int n_edges = in_sizes[3];
  float* out = (float*)d_out;

  const int nbuck = (n_users + BUSERS - 1) >> BSHIFT;  // 1563
  const int npw = (n_items + MROWS - 1) / MROWS;       // 782
  const int epb = (n_edges + NBLK - 1) / NBLK;         // 6250
  const int n_scan = nbuck * NBLK;                     // 400128
  const int nb_scan = (n_scan + 1023) / 1024;          // 391

  // ---- workspace layout (256B-aligned) ----
  auto align256 = [](size_t x) { return (x + 255) & ~(size_t)255; };
  char* ws = (char*)d_ws;
  size_t off = 0;
  unsigned short* Pb = (unsigned short*)(ws + off);
  off = align256(off + (size_t)n_items * D * 2);  // 12.8 MB
  int* bcount = (int*)(ws + off);  off = align256(off + (size_t)n_scan * 4);
  int* base = (int*)(ws + off);    off = align256(off + (size_t)n_scan * 4);
  int2* sedge = (int2*)(ws + off); off = align256(off + (size_t)n_edges * 8);
  int* partials = (int*)(ws + off); off = align256(off + (size_t)nb_scan * 4);
  int* blockoff = (int*)(ws + off); off = align256(off + (size_t)nb_scan * 4);

  // 1) fused: pw GEMM (blocks [0,npw)) || bucket histograms ([npw, npw+NBLK))
  pw_hist_kernel<<<npw + NBLK, 256, 0, stream>>>(
      item_emb, weight, Pb, n_items, npw, adj_rows, bcount, n_edges, epb,
      nbuck);

  // 2) 3-kernel exclusive scan of bcount -> base (no inter-block comms)
  blocksum_kernel<<<nb_scan, 1024, 0, stream>>>(bcount, partials, n_scan);
  scanpart_kernel<<<1, 1024, 0, stream>>>(partials, blockoff, nb_scan);
  localscan_kernel<<<nb_scan, 1024, 0, stream>>>(bcount, blockoff, base,
                                                 n_scan);

  // 3) scatter edges into bucket-sorted order (no global atomics)
  scatter2_kernel<<<NBLK, 256, 0, stream>>>(adj_rows, adj_cols, adj_vals, base,
                                            sedge, n_edges, epb, nbuck);

  // 4) per-bucket counting-sort + quarter-wave register gather
  bucket_gather_kernel<<<nbuck, 256, 0, stream>>>(
      reinterpret_cast<const uint4*>(Pb), base, sedge, user_nj, out,
      n_users, n_edges, nbuck);
}

// Round 18
// 132.394 us; speedup vs baseline: 1.2099x; 1.1143x over previous
//
#include <hip/hip_runtime.h>
#include <hip/hip_bf16.h>

#define D 128        // EMBED == LAYER == 128
#define BSHIFT 6     // 64 users per bucket
#define BUSERS (1 << BSHIFT)
#define NBLK 256     // blocks for hist/scatter passes
#define CHUNK 1280   // edges staged per bucket-chunk (avg bucket ~1024)
#define MROWS 64     // pw: item rows per block

typedef __attribute__((ext_vector_type(8))) short bf16x8;
typedef __attribute__((ext_vector_type(4))) float f32x4;

// round-to-nearest f32 -> bf16 bits
__device__ __forceinline__ unsigned int bf16rn(float f) {
  unsigned int u = __float_as_uint(f);
  return (u + 0x7fffu + ((u >> 16) & 1u)) >> 16;
}

// ---------------------------------------------------------------------------
// Kernel 1 (fused): blocks [0, npw) run the MFMA pw GEMM; blocks [npw,
// npw+NBLK) run the bucket histogram (proven r13).
// ---------------------------------------------------------------------------
__global__ __launch_bounds__(256) void pw_hist_kernel(
    const float* __restrict__ emb, const float* __restrict__ W,
    unsigned short* __restrict__ Pb, int n_items, int npw,
    const int* __restrict__ rows, int* __restrict__ bcount, int n_edges,
    int epb, int nbuck) {
  __shared__ __align__(16) char smem[49152];
  const int tid = threadIdx.x;

  if ((int)blockIdx.x < npw) {
    unsigned short* Wt = (unsigned short*)smem;            // 32 KB swizzled
    unsigned short* At = (unsigned short*)(smem + 32768);  // 16 KB swizzled
    const int m0 = blockIdx.x * MROWS;

    for (int i = tid; i < 128 * 128; i += 256) {
      const int k = i >> 7, c = i & 127;
      const unsigned short v = (unsigned short)bf16rn(W[i]);
      const int boff = c * 256 + ((2 * k) ^ ((c & 7) << 4));
      *reinterpret_cast<unsigned short*>(reinterpret_cast<char*>(Wt) + boff) = v;
    }
    for (int i = tid; i < MROWS * 128; i += 256) {
      const int r = i >> 7, k = i & 127;
      const int gr = m0 + r;
      const float f = (gr < n_items) ? emb[(size_t)gr * 128 + k] : 0.f;
      const unsigned short v = (unsigned short)bf16rn(f);
      const int boff = r * 256 + ((2 * k) ^ ((r & 7) << 4));
      *reinterpret_cast<unsigned short*>(reinterpret_cast<char*>(At) + boff) = v;
    }
    __syncthreads();

    const int w = tid >> 6;
    const int lane = tid & 63;
    const int lr = lane & 15;
    const int lg = lane >> 4;

    bf16x8 a[4];
    {
      const int rloc = w * 16 + lr;
#pragma unroll
      for (int ks = 0; ks < 4; ++ks) {
        const int boff = rloc * 256 + (((ks * 64) + lg * 16) ^ ((lr & 7) << 4));
        a[ks] = *reinterpret_cast<const bf16x8*>(
            reinterpret_cast<const char*>(At) + boff);
      }
    }

    f32x4 acc[8];
#pragma unroll
    for (int cs = 0; cs < 8; ++cs) acc[cs] = {0.f, 0.f, 0.f, 0.f};

#pragma unroll
    for (int cs = 0; cs < 8; ++cs) {
      const int c = cs * 16 + lr;
#pragma unroll
      for (int ks = 0; ks < 4; ++ks) {
        const int boff = c * 256 + (((ks * 64) + lg * 16) ^ ((lr & 7) << 4));
        const bf16x8 b = *reinterpret_cast<const bf16x8*>(
            reinterpret_cast<const char*>(Wt) + boff);
        acc[cs] = __builtin_amdgcn_mfma_f32_16x16x32_bf16(a[ks], b, acc[cs],
                                                          0, 0, 0);
      }
    }

#pragma unroll
    for (int cs = 0; cs < 8; ++cs) {
      const int c = cs * 16 + lr;
#pragma unroll
      for (int reg = 0; reg < 4; ++reg) {
        const int r = m0 + w * 16 + lg * 4 + reg;
        if (r < n_items)
          Pb[(size_t)r * 128 + c] = (unsigned short)bf16rn(acc[cs][reg]);
      }
    }
  } else {
    int* h = (int*)smem;
    const int hb = blockIdx.x - npw;
    for (int b = tid; b < nbuck; b += 256) h[b] = 0;
    __syncthreads();
    const int e0 = hb * epb;
    const int e1 = (e0 + epb < n_edges) ? e0 + epb : n_edges;
    for (int e = e0 + tid; e < e1; e += 256)
      atomicAdd(&h[rows[e] >> BSHIFT], 1);
    __syncthreads();
    for (int b = tid; b < nbuck; b += 256)
      bcount[(size_t)b * NBLK + hb] = h[b];
  }
}

// ---------------------------------------------------------------------------
// 3-kernel exclusive scan over bcount (nbuck*NBLK entries) -> base.
// ---------------------------------------------------------------------------
__global__ __launch_bounds__(1024) void blocksum_kernel(
    const int* __restrict__ in, int* __restrict__ partials, int n) {
  __shared__ int lds[1024];
  const int tid = threadIdx.x;
  const int i = blockIdx.x * 1024 + tid;
  lds[tid] = (i < n) ? in[i] : 0;
  __syncthreads();
  for (int s = 512; s > 0; s >>= 1) {
    if (tid < s) lds[tid] += lds[tid + s];
    __syncthreads();
  }
  if (tid == 0) partials[blockIdx.x] = lds[0];
}

__global__ __launch_bounds__(1024) void scanpart_kernel(
    const int* __restrict__ partials, int* __restrict__ blockoff, int nb) {
  __shared__ int lds[1024];
  const int tid = threadIdx.x;
  const int x = (tid < nb) ? partials[tid] : 0;
  lds[tid] = x;
  __syncthreads();
  for (int s = 1; s < 1024; s <<= 1) {
    const int y = (tid >= s) ? lds[tid - s] : 0;
    __syncthreads();
    lds[tid] += y;
    __syncthreads();
  }
  if (tid < nb) blockoff[tid] = lds[tid] - x;
}

__global__ __launch_bounds__(1024) void localscan_kernel(
    const int* __restrict__ in, const int* __restrict__ blockoff,
    int* __restrict__ base, int n) {
  __shared__ int lds[1024];
  const int tid = threadIdx.x;
  const int i = blockIdx.x * 1024 + tid;
  const int x = (i < n) ? in[i] : 0;
  lds[tid] = x;
  __syncthreads();
  for (int s = 1; s < 1024; s <<= 1) {
    const int y = (tid >= s) ? lds[tid - s] : 0;
    __syncthreads();
    lds[tid] += y;
    __syncthreads();
  }
  if (i < n) base[i] = blockoff[blockIdx.x] + lds[tid] - x;
}

// ---------------------------------------------------------------------------
// Kernel 3: scatter pass — LDS cursors seeded by scanned base.
// ---------------------------------------------------------------------------
__global__ __launch_bounds__(256) void scatter2_kernel(
    const int* __restrict__ rows, const int* __restrict__ cols,
    const float* __restrict__ vals, const int* __restrict__ base,
    int2* __restrict__ sedge, int n_edges, int epb, int nbuck) {
  __shared__ int cur[1600];
  const int tid = threadIdx.x;
  for (int b = tid; b < nbuck; b += 256)
    cur[b] = base[(size_t)b * NBLK + blockIdx.x];
  __syncthreads();
  const int e0 = blockIdx.x * epb;
  const int e1 = (e0 + epb < n_edges) ? e0 + epb : n_edges;
  for (int e = e0 + tid; e < e1; e += 256) {
    const int r = rows[e];
    const int pos = atomicAdd(&cur[r >> BSHIFT], 1);
    sedge[pos] =
        make_int2(((r & (BUSERS - 1)) << 16) | cols[e], __float_as_int(vals[e]));
  }
}

// ---------------------------------------------------------------------------
// Kernel 4: per-bucket 64-key LDS counting-sort + register accumulation.
// Quarter-wave per user, but with WAVE-UNIFORM loop bounds: all 4 groups of a
// wave iterate in lockstep to the max segment length (per-edge predication),
// so the wave genuinely keeps 4 groups x 8 = 32 P-row loads in flight
// (previous versions serialized the groups via divergent loop bounds).
// ---------------------------------------------------------------------------
__global__ __launch_bounds__(256) void bucket_gather_kernel(
    const uint4* __restrict__ Pb4,  // bf16, 16 uint4 per 256-B row
    const int* __restrict__ base, const int2* __restrict__ sedge,
    const float* __restrict__ nj, float* __restrict__ out, int n_users,
    int n_edges, int nbuck) {
  __shared__ int2 eraw[CHUNK];    // 10 KB
  __shared__ int2 esort[CHUNK];   // 10 KB
  __shared__ int cnt[BUSERS];
  __shared__ int incl[BUSERS];

  const int tid = threadIdx.x;
  const int b = blockIdx.x;
  const int u0 = b << BSHIFT;
  const int qw = tid >> 4;        // quarter-wave 0..15
  const int l16 = tid & 15;       // lane within quarter-wave

  const int beg = base[(size_t)b * NBLK];
  const int end = (b + 1 < nbuck) ? base[(size_t)(b + 1) * NBLK] : n_edges;

  float4 acc0[4], acc1[4];        // 4 users x 8 cols
#pragma unroll
  for (int k = 0; k < 4; ++k) {
    acc0[k] = {0.f, 0.f, 0.f, 0.f};
    acc1[k] = {0.f, 0.f, 0.f, 0.f};
  }

  for (int cbeg = beg; cbeg < end; cbeg += CHUNK) {
    const int cnum = (cbeg + CHUNK < end) ? CHUNK : (end - cbeg);
    if (tid < BUSERS) cnt[tid] = 0;
    __syncthreads();
    for (int i = tid; i < cnum; i += 256) {
      const int2 e = sedge[cbeg + i];
      eraw[i] = e;
      atomicAdd(&cnt[((unsigned int)e.x) >> 16], 1);
    }
    __syncthreads();
    if (tid < BUSERS) incl[tid] = cnt[tid];
    __syncthreads();
    for (int s = 1; s < BUSERS; s <<= 1) {
      int y = 0;
      if (tid < BUSERS && tid >= s) y = incl[tid - s];
      __syncthreads();
      if (tid < BUSERS) incl[tid] += y;
      __syncthreads();
    }
    if (tid < BUSERS) cnt[tid] = incl[tid] - cnt[tid];
    __syncthreads();
    for (int i = tid; i < cnum; i += 256) {
      const int2 e = eraw[i];
      const int pos = atomicAdd(&cnt[((unsigned int)e.x) >> 16], 1);
      esort[pos] = e;
    }
    __syncthreads();

    // register accumulate: lockstep groups, predicated edges
    if (cnum > 0) {
#pragma unroll
      for (int k = 0; k < 4; ++k) {
        const int ul = qw * 4 + k;
        const int s = (ul == 0) ? 0 : incl[ul - 1];
        const int t = incl[ul];
        // wave-uniform max segment length across this wave's 4 groups
        const int ub = ((qw >> 2) << 4) + k;   // wave*16 + k
        int wlen = 0;
#pragma unroll
        for (int m = 0; m < 4; ++m) {
          const int u2 = ub + m * 4;
          const int s2 = (u2 == 0) ? 0 : incl[u2 - 1];
          const int l2 = incl[u2] - s2;
          wlen = (l2 > wlen) ? l2 : wlen;
        }
        for (int i = 0; i < wlen; i += 8) {
          int2 e[8];
          uint4 p[8];
          float vv[8];
#pragma unroll
          for (int q = 0; q < 8; ++q) {
            const int j = s + i + q;
            const bool ok = (j < t);
            e[q] = esort[ok ? j : 0];
            vv[q] = ok ? __int_as_float(e[q].y) : 0.f;
          }
#pragma unroll
          for (int q = 0; q < 8; ++q)
            p[q] = Pb4[(size_t)(e[q].x & 0xffff) * 16 + l16];
#pragma unroll
          for (int q = 0; q < 8; ++q) {
            const float v = vv[q];
            acc0[k].x += v * __uint_as_float(p[q].x << 16);
            acc0[k].y += v * __uint_as_float(p[q].x & 0xffff0000u);
            acc0[k].z += v * __uint_as_float(p[q].y << 16);
            acc0[k].w += v * __uint_as_float(p[q].y & 0xffff0000u);
            acc1[k].x += v * __uint_as_float(p[q].z << 16);
            acc1[k].y += v * __uint_as_float(p[q].z & 0xffff0000u);
            acc1[k].z += v * __uint_as_float(p[q].w << 16);
            acc1[k].w += v * __uint_as_float(p[q].w & 0xffff0000u);
          }
        }
      }
    }
    __syncthreads();  // protect LDS before next chunk
  }

  // epilogue: scale by nj, two coalesced float4 stores per lane
#pragma unroll
  for (int k = 0; k < 4; ++k) {
    const int u = u0 + qw * 4 + k;
    if (u < n_users) {
      const float s = nj[u];
      float4 a0 = acc0[k], a1 = acc1[k];
      a0.x *= s; a0.y *= s; a0.z *= s; a0.w *= s;
      a1.x *= s; a1.y *= s; a1.z *= s; a1.w *= s;
      float* o = out + (size_t)u * D + l16 * 8;
      *reinterpret_cast<float4*>(o) = a0;
      *reinterpret_cast<float4*>(o + 4) = a1;
    }
  }
}

extern "C" void kernel_launch(void* const* d_in, const int* in_sizes, int n_in,
                              void* d_out, int out_size, void* d_ws,
                              size_t ws_size, hipStream_t stream) {
  const float* item_emb = (const float*)d_in[0];  // [n_items, 128]
  const float* user_nj  = (const float*)d_in[1];  // [n_users, 1]
  const float* weight   = (const float*)d_in[2];  // [128, 128]
  const float* adj_vals = (const float*)d_in[3];  // [E]
  const int*   adj_rows = (const int*)d_in[4];    // [E]
  const int*   adj_cols = (const int*)d_in[5];    // [E]

  const int n_items = in_sizes[0] / D;
  const int n_users = in_sizes[1];
  const int n_edges = in_sizes[3];
  float* out = (float*)d_out;

  const int nbuck = (n_users + BUSERS - 1) >> BSHIFT;  // 1563
  const int npw = (n_items + MROWS - 1) / MROWS;       // 782
  const int epb = (n_edges + NBLK - 1) / NBLK;         // 6250
  const int n_scan = nbuck * NBLK;                     // 400128
  const int nb_scan = (n_scan + 1023) / 1024;          // 391

  // ---- workspace layout (256B-aligned) ----
  auto align256 = [](size_t x) { return (x + 255) & ~(size_t)255; };
  char* ws = (char*)d_ws;
  size_t off = 0;
  unsigned short* Pb = (unsigned short*)(ws + off);
  off = align256(off + (size_t)n_items * D * 2);  // 12.8 MB
  int* bcount = (int*)(ws + off);  off = align256(off + (size_t)n_scan * 4);
  int* base = (int*)(ws + off);    off = align256(off + (size_t)n_scan * 4);
  int2* sedge = (int2*)(ws + off); off = align256(off + (size_t)n_edges * 8);
  int* partials = (int*)(ws + off); off = align256(off + (size_t)nb_scan * 4);
  int* blockoff = (int*)(ws + off); off = align256(off + (size_t)nb_scan * 4);

  // 1) fused: pw GEMM (blocks [0,npw)) || bucket histograms ([npw, npw+NBLK))
  pw_hist_kernel<<<npw + NBLK, 256, 0, stream>>>(
      item_emb, weight, Pb, n_items, npw, adj_rows, bcount, n_edges, epb,
      nbuck);

  // 2) 3-kernel exclusive scan of bcount -> base (no inter-block comms)
  blocksum_kernel<<<nb_scan, 1024, 0, stream>>>(bcount, partials, n_scan);
  scanpart_kernel<<<1, 1024, 0, stream>>>(partials, blockoff, nb_scan);
  localscan_kernel<<<nb_scan, 1024, 0, stream>>>(bcount, blockoff, base,
                                                 n_scan);

  // 3) scatter edges into bucket-sorted order (no global atomics)
  scatter2_kernel<<<NBLK, 256, 0, stream>>>(adj_rows, adj_cols, adj_vals, base,
                                            sedge, n_edges, epb, nbuck);

  // 4) per-bucket counting-sort + lockstep quarter-wave register gather
  bucket_gather_kernel<<<nbuck, 256, 0, stream>>>(
      reinterpret_cast<const uint4*>(Pb), base, sedge, user_nj, out,
      n_users, n_edges, nbuck);
}

// Round 20
// 111.442 us; speedup vs baseline: 1.4374x; 1.1880x over previous
//
#include <hip/hip_runtime.h>
#include <hip/hip_bf16.h>

#define D 128        // EMBED == LAYER == 128
#define BSHIFT 6     // 64 users per bucket
#define BUSERS (1 << BSHIFT)
#define NBLK 256     // blocks for hist/scatter passes
#define CHUNK 1280   // edges staged per bucket-chunk (avg bucket ~1024)
#define MROWS 64     // pw: item rows per block

typedef __attribute__((ext_vector_type(8))) short bf16x8;
typedef __attribute__((ext_vector_type(4))) float f32x4;

// round-to-nearest f32 -> bf16 bits
__device__ __forceinline__ unsigned int bf16rn(float f) {
  unsigned int u = __float_as_uint(f);
  return (u + 0x7fffu + ((u >> 16) & 1u)) >> 16;
}

// ---------------------------------------------------------------------------
// pw tile body (device fn): P[m0:m0+64] = emb @ W, MFMA bf16.
// Wt (32 KB LDS) staged cooperatively; A-fragments loaded DIRECT from global
// (f32->bf16 in-register) — no A staging, LDS halved -> 5 blocks/CU.
// ---------------------------------------------------------------------------
__device__ __forceinline__ void pw_tile(
    const float* __restrict__ emb, const float* __restrict__ W,
    unsigned short* __restrict__ Pb, int n_items, int tile,
    unsigned short* Wt /* 128*128 shorts, swizzled */) {
  const int tid = threadIdx.x;
  const int m0 = tile * MROWS;

  // stage W^T bf16 swizzled: Wt[c][k], boff = c*256 + ((2k)^((c&7)<<4))
  for (int i = tid; i < 128 * 128; i += 256) {
    const int k = i >> 7, c = i & 127;
    const unsigned short v = (unsigned short)bf16rn(W[i]);
    const int boff = c * 256 + ((2 * k) ^ ((c & 7) << 4));
    *reinterpret_cast<unsigned short*>(reinterpret_cast<char*>(Wt) + boff) = v;
  }

  const int w = tid >> 6;
  const int lane = tid & 63;
  const int lr = lane & 15;
  const int lg = lane >> 4;

  // A fragments direct from global: row gr, k = ks*32 + lg*8 + j
  bf16x8 a[4];
  const int gr = m0 + w * 16 + lr;
#pragma unroll
  for (int ks = 0; ks < 4; ++ks) {
    float4 f0 = {0.f, 0.f, 0.f, 0.f}, f1 = {0.f, 0.f, 0.f, 0.f};
    if (gr < n_items) {
      const float* p = emb + (size_t)gr * 128 + ks * 32 + lg * 8;
      f0 = *reinterpret_cast<const float4*>(p);
      f1 = *reinterpret_cast<const float4*>(p + 4);
    }
    bf16x8 av;
    av[0] = (short)bf16rn(f0.x); av[1] = (short)bf16rn(f0.y);
    av[2] = (short)bf16rn(f0.z); av[3] = (short)bf16rn(f0.w);
    av[4] = (short)bf16rn(f1.x); av[5] = (short)bf16rn(f1.y);
    av[6] = (short)bf16rn(f1.z); av[7] = (short)bf16rn(f1.w);
    a[ks] = av;
  }
  __syncthreads();  // Wt ready

  f32x4 acc[8];
#pragma unroll
  for (int cs = 0; cs < 8; ++cs) acc[cs] = {0.f, 0.f, 0.f, 0.f};

#pragma unroll
  for (int cs = 0; cs < 8; ++cs) {
    const int c = cs * 16 + lr;
#pragma unroll
    for (int ks = 0; ks < 4; ++ks) {
      const int boff = c * 256 + (((ks * 64) + lg * 16) ^ ((lr & 7) << 4));
      const bf16x8 b = *reinterpret_cast<const bf16x8*>(
          reinterpret_cast<const char*>(Wt) + boff);
      acc[cs] = __builtin_amdgcn_mfma_f32_16x16x32_bf16(a[ks], b, acc[cs],
                                                        0, 0, 0);
    }
  }

#pragma unroll
  for (int cs = 0; cs < 8; ++cs) {
    const int c = cs * 16 + lr;
#pragma unroll
    for (int reg = 0; reg < 4; ++reg) {
      const int r = m0 + w * 16 + lg * 4 + reg;
      if (r < n_items)
        Pb[(size_t)r * 128 + c] = (unsigned short)bf16rn(acc[cs][reg]);
    }
  }
}

// ---------------------------------------------------------------------------
// Kernel 1 (fused): blocks [0, npw1) -> pw tiles [0,npw1); blocks
// [npw1, npw1+NBLK) -> bucket histogram.
// ---------------------------------------------------------------------------
__global__ __launch_bounds__(256) void pw_hist_kernel(
    const float* __restrict__ emb, const float* __restrict__ W,
    unsigned short* __restrict__ Pb, int n_items, int npw1,
    const int* __restrict__ rows, int* __restrict__ bcount, int n_edges,
    int epb, int nbuck) {
  __shared__ __align__(16) char smem[32768];
  const int tid = threadIdx.x;

  if ((int)blockIdx.x < npw1) {
    pw_tile(emb, W, Pb, n_items, blockIdx.x, (unsigned short*)smem);
  } else {
    int* h = (int*)smem;
    const int hb = blockIdx.x - npw1;
    for (int b = tid; b < nbuck; b += 256) h[b] = 0;
    __syncthreads();
    const int e0 = hb * epb;
    const int e1 = (e0 + epb < n_edges) ? e0 + epb : n_edges;
    for (int e = e0 + tid; e < e1; e += 256)
      atomicAdd(&h[rows[e] >> BSHIFT], 1);
    __syncthreads();
    for (int b = tid; b < nbuck; b += 256)
      bcount[(size_t)b * NBLK + hb] = h[b];
  }
}

// ---------------------------------------------------------------------------
// 3-kernel exclusive scan over bcount (nbuck*NBLK entries) -> base.
// ---------------------------------------------------------------------------
__global__ __launch_bounds__(1024) void blocksum_kernel(
    const int* __restrict__ in, int* __restrict__ partials, int n) {
  __shared__ int lds[1024];
  const int tid = threadIdx.x;
  const int i = blockIdx.x * 1024 + tid;
  lds[tid] = (i < n) ? in[i] : 0;
  __syncthreads();
  for (int s = 512; s > 0; s >>= 1) {
    if (tid < s) lds[tid] += lds[tid + s];
    __syncthreads();
  }
  if (tid == 0) partials[blockIdx.x] = lds[0];
}

__global__ __launch_bounds__(1024) void scanpart_kernel(
    const int* __restrict__ partials, int* __restrict__ blockoff, int nb) {
  __shared__ int lds[1024];
  const int tid = threadIdx.x;
  const int x = (tid < nb) ? partials[tid] : 0;
  lds[tid] = x;
  __syncthreads();
  for (int s = 1; s < 1024; s <<= 1) {
    const int y = (tid >= s) ? lds[tid - s] : 0;
    __syncthreads();
    lds[tid] += y;
    __syncthreads();
  }
  if (tid < nb) blockoff[tid] = lds[tid] - x;
}

__global__ __launch_bounds__(1024) void localscan_kernel(
    const int* __restrict__ in, const int* __restrict__ blockoff,
    int* __restrict__ base, int n) {
  __shared__ int lds[1024];
  const int tid = threadIdx.x;
  const int i = blockIdx.x * 1024 + tid;
  const int x = (i < n) ? in[i] : 0;
  lds[tid] = x;
  __syncthreads();
  for (int s = 1; s < 1024; s <<= 1) {
    const int y = (tid >= s) ? lds[tid - s] : 0;
    __syncthreads();
    lds[tid] += y;
    __syncthreads();
  }
  if (i < n) base[i] = blockoff[blockIdx.x] + lds[tid] - x;
}

// ---------------------------------------------------------------------------
// Kernel 3 (fused): blocks [0, NBLK) -> scatter pass; blocks [NBLK,
// NBLK+npw2) -> pw tiles [npw1, npw).
// ---------------------------------------------------------------------------
__global__ __launch_bounds__(256) void scatter_pw_kernel(
    const int* __restrict__ rows, const int* __restrict__ cols,
    const float* __restrict__ vals, const int* __restrict__ base,
    int2* __restrict__ sedge, int n_edges, int epb, int nbuck,
    const float* __restrict__ emb, const float* __restrict__ W,
    unsigned short* __restrict__ Pb, int n_items, int npw1) {
  __shared__ __align__(16) char smem[32768];
  const int tid = threadIdx.x;

  if ((int)blockIdx.x >= NBLK) {
    pw_tile(emb, W, Pb, n_items, npw1 + (int)blockIdx.x - NBLK,
            (unsigned short*)smem);
    return;
  }
  int* cur = (int*)smem;
  for (int b = tid; b < nbuck; b += 256)
    cur[b] = base[(size_t)b * NBLK + blockIdx.x];
  __syncthreads();
  const int e0 = blockIdx.x * epb;
  const int e1 = (e0 + epb < n_edges) ? e0 + epb : n_edges;
  for (int e = e0 + tid; e < e1; e += 256) {
    const int r = rows[e];
    const int pos = atomicAdd(&cur[r >> BSHIFT], 1);
    sedge[pos] =
        make_int2(((r & (BUSERS - 1)) << 16) | cols[e], __float_as_int(vals[e]));
  }
}

// ---------------------------------------------------------------------------
// Kernel 4: per-bucket 64-key LDS counting-sort + lockstep quarter-wave
// register accumulation (proven r18: wave-uniform bounds keep 32 loads in
// flight per wave).
// ---------------------------------------------------------------------------
__global__ __launch_bounds__(256) void bucket_gather_kernel(
    const uint4* __restrict__ Pb4,  // bf16, 16 uint4 per 256-B row
    const int* __restrict__ base, const int2* __restrict__ sedge,
    const float* __restrict__ nj, float* __restrict__ out, int n_users,
    int n_edges, int nbuck) {
  __shared__ int2 eraw[CHUNK];    // 10 KB
  __shared__ int2 esort[CHUNK];   // 10 KB
  __shared__ int cnt[BUSERS];
  __shared__ int incl[BUSERS];

  const int tid = threadIdx.x;
  const int b = blockIdx.x;
  const int u0 = b << BSHIFT;
  const int qw = tid >> 4;        // quarter-wave 0..15
  const int l16 = tid & 15;       // lane within quarter-wave

  const int beg = base[(size_t)b * NBLK];
  const int end = (b + 1 < nbuck) ? base[(size_t)(b + 1) * NBLK] : n_edges;

  float4 acc0[4], acc1[4];        // 4 users x 8 cols
#pragma unroll
  for (int k = 0; k < 4; ++k) {
    acc0[k] = {0.f, 0.f, 0.f, 0.f};
    acc1[k] = {0.f, 0.f, 0.f, 0.f};
  }

  for (int cbeg = beg; cbeg < end; cbeg += CHUNK) {
    const int cnum = (cbeg + CHUNK < end) ? CHUNK : (end - cbeg);
    if (tid < BUSERS) cnt[tid] = 0;
    __syncthreads();
    for (int i = tid; i < cnum; i += 256) {
      const int2 e = sedge[cbeg + i];
      eraw[i] = e;
      atomicAdd(&cnt[((unsigned int)e.x) >> 16], 1);
    }
    __syncthreads();
    if (tid < BUSERS) incl[tid] = cnt[tid];
    __syncthreads();
    for (int s = 1; s < BUSERS; s <<= 1) {
      int y = 0;
      if (tid < BUSERS && tid >= s) y = incl[tid - s];
      __syncthreads();
      if (tid < BUSERS) incl[tid] += y;
      __syncthreads();
    }
    if (tid < BUSERS) cnt[tid] = incl[tid] - cnt[tid];
    __syncthreads();
    for (int i = tid; i < cnum; i += 256) {
      const int2 e = eraw[i];
      const int pos = atomicAdd(&cnt[((unsigned int)e.x) >> 16], 1);
      esort[pos] = e;
    }
    __syncthreads();

    // register accumulate: lockstep groups, predicated edges
    if (cnum > 0) {
#pragma unroll
      for (int k = 0; k < 4; ++k) {
        const int ul = qw * 4 + k;
        const int s = (ul == 0) ? 0 : incl[ul - 1];
        const int t = incl[ul];
        // wave-uniform max segment length across this wave's 4 groups
        const int ub = ((qw >> 2) << 4) + k;   // wave*16 + k
        int wlen = 0;
#pragma unroll
        for (int m = 0; m < 4; ++m) {
          const int u2 = ub + m * 4;
          const int s2 = (u2 == 0) ? 0 : incl[u2 - 1];
          const int l2 = incl[u2] - s2;
          wlen = (l2 > wlen) ? l2 : wlen;
        }
        for (int i = 0; i < wlen; i += 8) {
          int2 e[8];
          uint4 p[8];
          float vv[8];
#pragma unroll
          for (int q = 0; q < 8; ++q) {
            const int j = s + i + q;
            const bool ok = (j < t);
            e[q] = esort[ok ? j : 0];
            vv[q] = ok ? __int_as_float(e[q].y) : 0.f;
          }
#pragma unroll
          for (int q = 0; q < 8; ++q)
            p[q] = Pb4[(size_t)(e[q].x & 0xffff) * 16 + l16];
#pragma unroll
          for (int q = 0; q < 8; ++q) {
            const float v = vv[q];
            acc0[k].x += v * __uint_as_float(p[q].x << 16);
            acc0[k].y += v * __uint_as_float(p[q].x & 0xffff0000u);
            acc0[k].z += v * __uint_as_float(p[q].y << 16);
            acc0[k].w += v * __uint_as_float(p[q].y & 0xffff0000u);
            acc1[k].x += v * __uint_as_float(p[q].z << 16);
            acc1[k].y += v * __uint_as_float(p[q].z & 0xffff0000u);
            acc1[k].z += v * __uint_as_float(p[q].w << 16);
            acc1[k].w += v * __uint_as_float(p[q].w & 0xffff0000u);
          }
        }
      }
    }
    __syncthreads();  // protect LDS before next chunk
  }

  // epilogue: scale by nj, two coalesced float4 stores per lane
#pragma unroll
  for (int k = 0; k < 4; ++k) {
    const int u = u0 + qw * 4 + k;
    if (u < n_users) {
      const float s = nj[u];
      float4 a0 = acc0[k], a1 = acc1[k];
      a0.x *= s; a0.y *= s; a0.z *= s; a0.w *= s;
      a1.x *= s; a1.y *= s; a1.z *= s; a1.w *= s;
      float* o = out + (size_t)u * D + l16 * 8;
      *reinterpret_cast<float4*>(o) = a0;
      *reinterpret_cast<float4*>(o + 4) = a1;
    }
  }
}

extern "C" void kernel_launch(void* const* d_in, const int* in_sizes, int n_in,
                              void* d_out, int out_size, void* d_ws,
                              size_t ws_size, hipStream_t stream) {
  const float* item_emb = (const float*)d_in[0];  // [n_items, 128]
  const float* user_nj  = (const float*)d_in[1];  // [n_users, 1]
  const float* weight   = (const float*)d_in[2];  // [128, 128]
  const float* adj_vals = (const float*)d_in[3];  // [E]
  const int*   adj_rows = (const int*)d_in[4];    // [E]
  const int*   adj_cols = (const int*)d_in[5];    // [E]

  const int n_items = in_sizes[0] / D;
  const int n_users = in_sizes[1];
  const int n_edges = in_sizes[3];
  float* out = (float*)d_out;

  const int nbuck = (n_users + BUSERS - 1) >> BSHIFT;  // 1563
  const int npw = (n_items + MROWS - 1) / MROWS;       // 782
  const int npw1 = (npw + 1) / 2;                      // 391 (stage 1)
  const int npw2 = npw - npw1;                         // 391 (stage 3)
  const int epb = (n_edges + NBLK - 1) / NBLK;         // 6250
  const int n_scan = nbuck * NBLK;                     // 400128
  const int nb_scan = (n_scan + 1023) / 1024;          // 391

  // ---- workspace layout (256B-aligned) ----
  auto align256 = [](size_t x) { return (x + 255) & ~(size_t)255; };
  char* ws = (char*)d_ws;
  size_t off = 0;
  unsigned short* Pb = (unsigned short*)(ws + off);
  off = align256(off + (size_t)n_items * D * 2);  // 12.8 MB
  int* bcount = (int*)(ws + off);  off = align256(off + (size_t)n_scan * 4);
  int* base = (int*)(ws + off);    off = align256(off + (size_t)n_scan * 4);
  int2* sedge = (int2*)(ws + off); off = align256(off + (size_t)n_edges * 8);
  int* partials = (int*)(ws + off); off = align256(off + (size_t)nb_scan * 4);
  int* blockoff = (int*)(ws + off); off = align256(off + (size_t)nb_scan * 4);

  // 1) fused: pw tiles [0,npw1) || bucket histograms
  pw_hist_kernel<<<npw1 + NBLK, 256, 0, stream>>>(
      item_emb, weight, Pb, n_items, npw1, adj_rows, bcount, n_edges, epb,
      nbuck);

  // 2) 3-kernel exclusive scan of bcount -> base (no inter-block comms)
  blocksum_kernel<<<nb_scan, 1024, 0, stream>>>(bcount, partials, n_scan);
  scanpart_kernel<<<1, 1024, 0, stream>>>(partials, blockoff, nb_scan);
  localscan_kernel<<<nb_scan, 1024, 0, stream>>>(bcount, blockoff, base,
                                                 n_scan);

  // 3) fused: scatter pass || pw tiles [npw1, npw)
  scatter_pw_kernel<<<NBLK + npw2, 256, 0, stream>>>(
      adj_rows, adj_cols, adj_vals, base, sedge, n_edges, epb, nbuck,
      item_emb, weight, Pb, n_items, npw1);

  // 4) per-bucket counting-sort + lockstep quarter-wave register gather
  bucket_gather_kernel<<<nbuck, 256, 0, stream>>>(
      reinterpret_cast<const uint4*>(Pb), base, sedge, user_nj, out,
      n_users, n_edges, nbuck);
}